// Round 1
// baseline (620.837 us; speedup 1.0000x reference)
//
#include <hip/hip_runtime.h>
#include <math.h>

#define N_NODES 50000
#define N_EDGES 800000
#define ET (N_EDGES + N_NODES)   // edges + self loops
#define FDIM 512                 // HEADS*OUT_CH
#define NEG_SLOPE 0.2f

// ---------------------------------------------------------------------------
// Detect whether edge_index is stored as int64 (lo,hi pairs) or int32.
// If int64, every odd 32-bit word of the first 1024 elements is the hi word
// of a value < 50000 -> zero. For int32 data those words are random node ids
// (P(all zero) ~ (2e-5)^1024 ~ 0).
__global__ void detect_i64_kernel(const int* __restrict__ ei, int* __restrict__ flag) {
    __shared__ int bad_sh[256];
    int t = threadIdx.x;
    int bad = 0;
    for (int i = t; i < 1024; i += 256)
        if (ei[2 * i + 1] != 0) bad = 1;
    bad_sh[t] = bad;
    __syncthreads();
    for (int s = 128; s > 0; s >>= 1) {
        if (t < s) bad_sh[t] |= bad_sh[t + s];
        __syncthreads();
    }
    if (t == 0) *flag = bad_sh[0] ? 0 : 1;   // 1 => int64 layout
}

__device__ __forceinline__ int load_src(const int* ei, int is64, int e) {
    if (e < N_EDGES) return is64 ? ei[2 * e] : ei[e];
    return e - N_EDGES;                       // self loop
}
__device__ __forceinline__ int load_dst(const int* ei, int is64, int e) {
    if (e < N_EDGES) return is64 ? ei[2 * (N_EDGES + e)] : ei[N_EDGES + e];
    return e - N_EDGES;                       // self loop
}

// ---------------------------------------------------------------------------
__global__ void count_deg_kernel(const int* __restrict__ ei, const int* __restrict__ flag,
                                 int* __restrict__ deg) {
    int is64 = *flag;
    for (int e = blockIdx.x * blockDim.x + threadIdx.x; e < ET; e += gridDim.x * blockDim.x) {
        int dst = load_dst(ei, is64, e);
        atomicAdd(&deg[dst], 1);
    }
}

// Single-block exclusive scan over 50000 degrees -> row_start[50001], cursor copy.
__global__ void scan_deg_kernel(const int* __restrict__ deg, int* __restrict__ row_start,
                                int* __restrict__ cursor) {
    __shared__ int sums[1024];
    int t = threadIdx.x;
    const int C = (N_NODES + 1023) / 1024;    // 49
    int lo = t * C;
    int hi = min(lo + C, N_NODES);
    int s = 0;
    for (int i = lo; i < hi; i++) s += deg[i];
    sums[t] = s;
    __syncthreads();
    // Hillis-Steele inclusive scan over 1024 thread sums
    for (int off = 1; off < 1024; off <<= 1) {
        int v = 0;
        if (t >= off) v = sums[t - off];
        __syncthreads();
        if (t >= off) sums[t] += v;
        __syncthreads();
    }
    int run = (t == 0) ? 0 : sums[t - 1];
    for (int i = lo; i < hi; i++) {
        row_start[i] = run;
        cursor[i]    = run;
        run += deg[i];
    }
    if (t == 1023) row_start[N_NODES] = sums[1023];
}

__global__ void fill_csr_kernel(const int* __restrict__ ei, const int* __restrict__ flag,
                                int* __restrict__ cursor, int* __restrict__ csr_src) {
    int is64 = *flag;
    for (int e = blockIdx.x * blockDim.x + threadIdx.x; e < ET; e += gridDim.x * blockDim.x) {
        int src = load_src(ei, is64, e);
        int dst = load_dst(ei, is64, e);
        int pos = atomicAdd(&cursor[dst], 1);
        csr_src[pos] = src;
    }
}

// ---------------------------------------------------------------------------
// x_l = feat @ W_l.  64 nodes per 256-thread block; thread t owns cols 2t,2t+1
// (W columns held in registers, reused across the 64 nodes).
__global__ __launch_bounds__(256) void gemm_xl_kernel(const float* __restrict__ feat,
                                                      const float* __restrict__ Wl,
                                                      float* __restrict__ xl) {
    __shared__ float fsh[64 * 16];
    int t = threadIdx.x;
    int node0 = blockIdx.x * 64;
    int nvalid = min(64, N_NODES - node0);

    float w0[16], w1[16];
#pragma unroll
    for (int k = 0; k < 16; k++) {
        float2 w = ((const float2*)(Wl + k * FDIM))[t];
        w0[k] = w.x; w1[k] = w.y;
    }
    if (t < nvalid * 4) {   // nvalid*16 floats = nvalid*4 float4
        ((float4*)fsh)[t] = ((const float4*)(feat + (size_t)node0 * 16))[t];
    }
    __syncthreads();

    for (int n = 0; n < nvalid; n++) {
        float a0 = 0.f, a1 = 0.f;
#pragma unroll
        for (int k = 0; k < 16; k++) {
            float f = fsh[n * 16 + k];
            a0 = fmaf(f, w0[k], a0);
            a1 = fmaf(f, w1[k], a1);
        }
        ((float2*)(xl + (size_t)(node0 + n) * FDIM))[t] = make_float2(a0, a1);
    }
}

// ---------------------------------------------------------------------------
// One wave per destination node. Online softmax over incoming edges.
// Lane l owns channels [8l, 8l+8) -> lanes [16h,16h+16) cover head h.
__global__ __launch_bounds__(256) void gat_aggregate_kernel(
        const float* __restrict__ feat, const float* __restrict__ Wr,
        const float* __restrict__ att,  const float* __restrict__ bias,
        const float* __restrict__ xl,   const int* __restrict__ row_start,
        const int* __restrict__ csr_src, float* __restrict__ out) {
    __shared__ float wr_sh[16 * FDIM];   // 32 KB
    __shared__ float att_sh[FDIM];
    __shared__ float bias_sh[FDIM];

    int t = threadIdx.x;
    for (int i = t; i < 16 * FDIM / 4; i += 256)
        ((float4*)wr_sh)[i] = ((const float4*)Wr)[i];
    if (t < FDIM / 4)        ((float4*)att_sh)[t]         = ((const float4*)att)[t];
    else if (t < FDIM / 2)   ((float4*)bias_sh)[t - 128]  = ((const float4*)bias)[t - 128];
    __syncthreads();

    int wave = t >> 6, lane = t & 63;
    int node = blockIdx.x * 4 + wave;
    if (node >= N_NODES) return;
    int cbase = lane * 8;

    // feat[node] (broadcast across lanes)
    float f[16];
    {
        const float4* fp = (const float4*)(feat + (size_t)node * 16);
        float4 f0 = fp[0], f1 = fp[1], f2 = fp[2], f3 = fp[3];
        f[0]=f0.x; f[1]=f0.y; f[2]=f0.z; f[3]=f0.w;
        f[4]=f1.x; f[5]=f1.y; f[6]=f1.z; f[7]=f1.w;
        f[8]=f2.x; f[9]=f2.y; f[10]=f2.z; f[11]=f2.w;
        f[12]=f3.x; f[13]=f3.y; f[14]=f3.z; f[15]=f3.w;
    }

    // x_r[node] for this lane's 8 channels, from LDS-staged W_r
    float xr[8];
#pragma unroll
    for (int j = 0; j < 8; j++) xr[j] = 0.f;
#pragma unroll
    for (int k = 0; k < 16; k++) {
        float fk = f[k];
        float4 wa = *(const float4*)(wr_sh + k * FDIM + cbase);
        float4 wb = *(const float4*)(wr_sh + k * FDIM + cbase + 4);
        xr[0] = fmaf(fk, wa.x, xr[0]); xr[1] = fmaf(fk, wa.y, xr[1]);
        xr[2] = fmaf(fk, wa.z, xr[2]); xr[3] = fmaf(fk, wa.w, xr[3]);
        xr[4] = fmaf(fk, wb.x, xr[4]); xr[5] = fmaf(fk, wb.y, xr[5]);
        xr[6] = fmaf(fk, wb.z, xr[6]); xr[7] = fmaf(fk, wb.w, xr[7]);
    }

    float a[8];
    {
        float4 a0 = *(const float4*)(att_sh + cbase);
        float4 a1 = *(const float4*)(att_sh + cbase + 4);
        a[0]=a0.x; a[1]=a0.y; a[2]=a0.z; a[3]=a0.w;
        a[4]=a1.x; a[5]=a1.y; a[6]=a1.z; a[7]=a1.w;
    }

    float m = -INFINITY, d = 0.f;
    float acc[8];
#pragma unroll
    for (int j = 0; j < 8; j++) acc[j] = 0.f;

    int e0 = row_start[node], e1 = row_start[node + 1];
    for (int k = e0; k < e1; k++) {
        int src = csr_src[k];
        const float* xp = xl + (size_t)src * FDIM + cbase;
        float4 x0 = *(const float4*)xp;
        float4 x1 = *(const float4*)(xp + 4);
        float xv[8] = {x0.x, x0.y, x0.z, x0.w, x1.x, x1.y, x1.z, x1.w};

        float p = 0.f;
#pragma unroll
        for (int j = 0; j < 8; j++) {
            float s = xv[j] + xr[j];
            float lr = s > 0.f ? s : NEG_SLOPE * s;
            p = fmaf(lr, a[j], p);
        }
        // reduce over the 16 lanes of this head
        p += __shfl_xor(p, 1);
        p += __shfl_xor(p, 2);
        p += __shfl_xor(p, 4);
        p += __shfl_xor(p, 8);

        float nm = fmaxf(m, p);
        float scale = __expf(m - nm);    // first iter: exp(-inf)=0
        float w = __expf(p - nm);
        d = d * scale + w;
#pragma unroll
        for (int j = 0; j < 8; j++) acc[j] = fmaf(acc[j], scale, w * xv[j]);
        m = nm;
    }

    float inv = 1.f / (d + 1e-16f);
    float o[8];
#pragma unroll
    for (int j = 0; j < 8; j++) o[j] = fmaf(acc[j], inv, bias_sh[cbase + j]);
    float* op = out + (size_t)node * FDIM + cbase;
    *(float4*)op       = make_float4(o[0], o[1], o[2], o[3]);
    *(float4*)(op + 4) = make_float4(o[4], o[5], o[6], o[7]);
}

// ---------------------------------------------------------------------------
extern "C" void kernel_launch(void* const* d_in, const int* in_sizes, int n_in,
                              void* d_out, int out_size, void* d_ws, size_t ws_size,
                              hipStream_t stream) {
    const float* feat = (const float*)d_in[0];
    const int*   ei   = (const int*)d_in[1];
    const float* Wl   = (const float*)d_in[2];
    const float* Wr   = (const float*)d_in[3];
    const float* att  = (const float*)d_in[4];
    const float* bias = (const float*)d_in[5];
    float* out = (float*)d_out;

    char* ws = (char*)d_ws;
    size_t off = 0;
    float* xl       = (float*)(ws + off); off += (size_t)N_NODES * FDIM * sizeof(float);
    int*   row_start= (int*)(ws + off);   off += (size_t)(N_NODES + 1) * sizeof(int);
    int*   cursor   = (int*)(ws + off);   off += (size_t)N_NODES * sizeof(int);
    int*   deg      = (int*)(ws + off);   off += (size_t)N_NODES * sizeof(int);
    int*   csr_src  = (int*)(ws + off);   off += (size_t)ET * sizeof(int);
    int*   flag     = (int*)(ws + off);   off += sizeof(int);
    (void)ws_size; (void)in_sizes; (void)n_in; (void)out_size;

    hipMemsetAsync(deg, 0, (size_t)N_NODES * sizeof(int), stream);
    detect_i64_kernel<<<1, 256, 0, stream>>>(ei, flag);
    gemm_xl_kernel<<<(N_NODES + 63) / 64, 256, 0, stream>>>(feat, Wl, xl);
    count_deg_kernel<<<512, 256, 0, stream>>>(ei, flag, deg);
    scan_deg_kernel<<<1, 1024, 0, stream>>>(deg, row_start, cursor);
    fill_csr_kernel<<<512, 256, 0, stream>>>(ei, flag, cursor, csr_src);
    gat_aggregate_kernel<<<(N_NODES + 3) / 4, 256, 0, stream>>>(
        feat, Wr, att, bias, xl, row_start, csr_src, out);
}